// Round 7
// baseline (480.961 us; speedup 1.0000x reference)
//
#include <hip/hip_runtime.h>
#include <hip/hip_bf16.h>
#include <stdint.h>

// Problem sizes (compile-time)
static constexpr int BATCH = 32768;
static constexpr int DIN   = 512;
static constexpr int DHID  = 1024;
static constexpr int DOUT  = 2048;

typedef __bf16 bf16x8 __attribute__((ext_vector_type(8)));
typedef float  f32x4  __attribute__((ext_vector_type(4)));

// fp32 -> bf16 round-to-nearest-even
__device__ __forceinline__ unsigned short f2bf(float f) {
    unsigned int u = __float_as_uint(f);
    u += 0x7FFFu + ((u >> 16) & 1u);
    return (unsigned short)(u >> 16);
}

// async global->LDS, 16B per lane. LDS dest = wave-uniform base + 16*lane.
__device__ __forceinline__ void gload_lds16(const void* g, void* l) {
    __builtin_amdgcn_global_load_lds((__attribute__((address_space(1))) void*)g,
                                     (__attribute__((address_space(3))) void*)l,
                                     16, 0, 0);
}

// ---------------------------------------------------------------------------
// Kernel 1: convert x, l1_w, weight fp32 -> bf16 into workspace
// ---------------------------------------------------------------------------
__global__ __launch_bounds__(256) void cvt_kernel(
    const float4* __restrict__ x, const float4* __restrict__ w1, const float4* __restrict__ w2,
    ushort4* __restrict__ xb, ushort4* __restrict__ w1b, ushort4* __restrict__ w2b) {
    const size_t NX  = (size_t)BATCH * DIN  / 4;
    const size_t NW1 = (size_t)DHID  * DIN  / 4;
    const size_t NW2 = (size_t)DOUT  * DHID / 4;
    size_t g = (size_t)blockIdx.x * blockDim.x + threadIdx.x;
    const float4* s; ushort4* d; size_t i;
    if (g < NX)                  { s = x;  d = xb;  i = g; }
    else if (g < NX + NW1)       { s = w1; d = w1b; i = g - NX; }
    else if (g < NX + NW1 + NW2) { s = w2; d = w2b; i = g - NX - NW1; }
    else return;
    float4 v = s[i];
    ushort4 o;
    o.x = f2bf(v.x); o.y = f2bf(v.y); o.z = f2bf(v.z); o.w = f2bf(v.w);
    d[i] = o;
}

// ===========================================================================
// Restructured GEMM (round 7): only A goes through LDS (+barrier); B (the
// small, L2-hot weight) is loaded DIRECTLY global->VGPR in MFMA fragment
// layout (B[n=lane&15][k=(lane>>4)*8+j] -> 16B/lane, 64B-coalesced per quad).
// This halves barrier-protected VMEM, shrinks LDS to 16KB (occupancy up),
// and gives the scheduler barrier-free VMEM to interleave with MFMA.
// A LDS tile: 128 rows x 64 bf16, swizzled slot = row*8 + (chunk ^ (row&7));
// fragment read chunk = (ks*4+q) ^ (r&7)  -> measured 0 bank conflicts.
// Grid is N-fastest for A-tile sharing among co-dispatched blocks.
// ===========================================================================

// ---------------------------------------------------------------------------
// GEMM1: h = x * l1_w^T + l1_b, bf16 out. BM=128, BN=128, BK=64.
// ---------------------------------------------------------------------------
__global__ __launch_bounds__(256) void gemm1_kernel(
    const unsigned short* __restrict__ A,   // x bf16 [BATCH, DIN]
    const unsigned short* __restrict__ Bw,  // l1_w bf16 [DHID, DIN]
    const float* __restrict__ l1b,          // [DHID]
    unsigned short* __restrict__ H) {       // out bf16 [BATCH, DHID]
    constexpr int K = DIN;
    __shared__ __align__(16) unsigned short sA[128 * 64];  // 16 KB

    const int tid  = threadIdx.x;
    const int lane = tid & 63;
    const int wid  = tid >> 6;
    const int wr = wid >> 1, wc = wid & 1;
    const int r = lane & 15, q = lane >> 4;
    const int sw = r & 7;
    const int blockN = blockIdx.x * 128;   // N-fastest
    const int blockM = blockIdx.y * 128;

    // A staging (swizzled, 4 issues/thread)
    const int chKey = (lane & 7) ^ ((lane >> 3) & 7);
    const size_t aBase = (size_t)(blockM + wid * 32 + (lane >> 3)) * K + chKey * 8;

    // B direct-fragment offsets (elements): row = blockN + wc*64 + nt*16 + r
    int bOff[4][2];
#pragma unroll
    for (int nt = 0; nt < 4; ++nt)
#pragma unroll
        for (int ks = 0; ks < 2; ++ks)
            bOff[nt][ks] = (blockN + wc * 64 + nt * 16 + r) * K + ks * 32 + q * 8;

    f32x4 acc[4][4];
#pragma unroll
    for (int mt = 0; mt < 4; ++mt)
#pragma unroll
        for (int nt = 0; nt < 4; ++nt) { f32x4 z = {0.f, 0.f, 0.f, 0.f}; acc[mt][nt] = z; }

    for (int k0 = 0; k0 < K; k0 += 64) {
#pragma unroll
        for (int j = 0; j < 4; ++j)
            gload_lds16(A + aBase + (size_t)j * 8 * K + k0, sA + wid * 2048 + j * 512);

        // B fragments: barrier-free global->VGPR (L2-hot weight)
        bf16x8 bf[4][2];
#pragma unroll
        for (int nt = 0; nt < 4; ++nt)
#pragma unroll
            for (int ks = 0; ks < 2; ++ks)
                bf[nt][ks] = *(const bf16x8*)(Bw + bOff[nt][ks] + k0);

        __syncthreads();
#pragma unroll
        for (int ks = 0; ks < 2; ++ks) {
            const int ch = ((ks << 2) + q) ^ sw;
            bf16x8 af[4];
#pragma unroll
            for (int mt = 0; mt < 4; ++mt) af[mt] = *(const bf16x8*)&sA[(wr * 64 + mt * 16 + r) * 64 + ch * 8];
#pragma unroll
            for (int mt = 0; mt < 4; ++mt)
#pragma unroll
                for (int nt = 0; nt < 4; ++nt)
                    acc[mt][nt] = __builtin_amdgcn_mfma_f32_16x16x32_bf16(af[mt], bf[nt][ks], acc[mt][nt], 0, 0, 0);
        }
        __syncthreads();
    }

    // Epilogue: +bias, convert, store. C/D: col = lane&15, row = q*4+reg.
    const int colBase = blockN + wc * 64;
    const int rowBase = blockM + wr * 64;
    float bv[4];
#pragma unroll
    for (int nt = 0; nt < 4; ++nt) bv[nt] = l1b[colBase + nt * 16 + r];
#pragma unroll
    for (int mt = 0; mt < 4; ++mt) {
        const int row0 = rowBase + mt * 16 + q * 4;
#pragma unroll
        for (int nt = 0; nt < 4; ++nt) {
            const int col = colBase + nt * 16 + r;
#pragma unroll
            for (int reg = 0; reg < 4; ++reg)
                H[(size_t)(row0 + reg) * DHID + col] = f2bf(acc[mt][nt][reg] + bv[nt]);
        }
    }
}

// ---------------------------------------------------------------------------
// GEMM2: scores = H * weight^T + bias, fused row-max. BM=128, BN=128, BK=64.
// A (H) via LDS; B (weight) direct-to-register. Two M-half dispatches.
// ---------------------------------------------------------------------------
__global__ __launch_bounds__(256) void gemm2_kernel(
    const unsigned short* __restrict__ A,   // H bf16 [BATCH, DHID]
    const unsigned short* __restrict__ Bw,  // weight bf16 [DOUT, DHID]
    const float* __restrict__ bias,         // [DOUT]
    float* __restrict__ partials,           // [BATCH, 32]
    int mBase) {
    constexpr int K = DHID;
    __shared__ __align__(16) unsigned short sA[128 * 64];  // 16 KB

    const int tid  = threadIdx.x;
    const int lane = tid & 63;
    const int wid  = tid >> 6;
    const int wr = wid >> 1, wc = wid & 1;
    const int r = lane & 15, q = lane >> 4;
    const int sw = r & 7;
    const int blockN = blockIdx.x * 128;   // N-fastest
    const int blockM = mBase + blockIdx.y * 128;

    const int chKey = (lane & 7) ^ ((lane >> 3) & 7);
    const size_t aBase = (size_t)(blockM + wid * 32 + (lane >> 3)) * K + chKey * 8;

    int bOff[4][2];
#pragma unroll
    for (int nt = 0; nt < 4; ++nt)
#pragma unroll
        for (int ks = 0; ks < 2; ++ks)
            bOff[nt][ks] = (blockN + wc * 64 + nt * 16 + r) * K + ks * 32 + q * 8;

    f32x4 acc[4][4];
#pragma unroll
    for (int mt = 0; mt < 4; ++mt)
#pragma unroll
        for (int nt = 0; nt < 4; ++nt) { f32x4 z = {0.f, 0.f, 0.f, 0.f}; acc[mt][nt] = z; }

    for (int k0 = 0; k0 < K; k0 += 64) {
#pragma unroll
        for (int j = 0; j < 4; ++j)
            gload_lds16(A + aBase + (size_t)j * 8 * K + k0, sA + wid * 2048 + j * 512);

        bf16x8 bf[4][2];
#pragma unroll
        for (int nt = 0; nt < 4; ++nt)
#pragma unroll
            for (int ks = 0; ks < 2; ++ks)
                bf[nt][ks] = *(const bf16x8*)(Bw + bOff[nt][ks] + k0);

        __syncthreads();
#pragma unroll
        for (int ks = 0; ks < 2; ++ks) {
            const int ch = ((ks << 2) + q) ^ sw;
            bf16x8 af[4];
#pragma unroll
            for (int mt = 0; mt < 4; ++mt) af[mt] = *(const bf16x8*)&sA[(wr * 64 + mt * 16 + r) * 64 + ch * 8];
#pragma unroll
            for (int mt = 0; mt < 4; ++mt)
#pragma unroll
                for (int nt = 0; nt < 4; ++nt)
                    acc[mt][nt] = __builtin_amdgcn_mfma_f32_16x16x32_bf16(af[mt], bf[nt][ks], acc[mt][nt], 0, 0, 0);
        }
        __syncthreads();
    }

    // Epilogue: +bias, max over the wave's 64 cols, 16-lane reduce, write partial.
    const int colBase = blockN + wc * 64;
    const int rowBase = blockM + wr * 64;
    float bv[4];
#pragma unroll
    for (int nt = 0; nt < 4; ++nt) bv[nt] = bias[colBase + nt * 16 + r];

    float mx[4][4];
#pragma unroll
    for (int mt = 0; mt < 4; ++mt)
#pragma unroll
        for (int reg = 0; reg < 4; ++reg) {
            float v = acc[mt][0][reg] + bv[0];
            v = fmaxf(v, acc[mt][1][reg] + bv[1]);
            v = fmaxf(v, acc[mt][2][reg] + bv[2]);
            v = fmaxf(v, acc[mt][3][reg] + bv[3]);
            mx[mt][reg] = v;
        }
#pragma unroll
    for (int off = 1; off < 16; off <<= 1)
#pragma unroll
        for (int mt = 0; mt < 4; ++mt)
#pragma unroll
            for (int reg = 0; reg < 4; ++reg)
                mx[mt][reg] = fmaxf(mx[mt][reg], __shfl_xor(mx[mt][reg], off));

    if (r == 0) {
#pragma unroll
        for (int mt = 0; mt < 4; ++mt)
#pragma unroll
            for (int reg = 0; reg < 4; ++reg) {
                const int row = rowBase + mt * 16 + q * 4 + reg;
                partials[(size_t)row * 32 + blockIdx.x * 2 + wc] = mx[mt][reg];
            }
    }
}

// ---------------------------------------------------------------------------
// Kernel 4: reduce 32 partials per row -> final max
// ---------------------------------------------------------------------------
__global__ __launch_bounds__(256) void reduce_kernel(
    const float4* __restrict__ partials, float* __restrict__ out) {
    const int row = blockIdx.x * blockDim.x + threadIdx.x;
    const float4* p = partials + (size_t)row * 8;
    float m = -INFINITY;
#pragma unroll
    for (int i = 0; i < 8; ++i) {
        float4 v = p[i];
        m = fmaxf(m, fmaxf(fmaxf(v.x, v.y), fmaxf(v.z, v.w)));
    }
    out[row] = m;
}

// ---------------------------------------------------------------------------
extern "C" void kernel_launch(void* const* d_in, const int* in_sizes, int n_in,
                              void* d_out, int out_size, void* d_ws, size_t ws_size,
                              hipStream_t stream) {
    const float* x   = (const float*)d_in[0];
    const float* l1w = (const float*)d_in[1];
    const float* l1b = (const float*)d_in[2];
    const float* w2  = (const float*)d_in[3];
    const float* b2  = (const float*)d_in[4];
    float* out = (float*)d_out;

    char* ws = (char*)d_ws;
    unsigned short* xb  = (unsigned short*)(ws);                 // 32 MB  x  bf16
    unsigned short* w1b = (unsigned short*)(ws + 33554432);      //  1 MB  l1_w bf16
    unsigned short* w2b = (unsigned short*)(ws + 34603008);      //  4 MB  weight bf16
    unsigned short* hb  = (unsigned short*)(ws + 38797312);      // 64 MB  h bf16
    float* partials     = (float*)(ws + 105906176);              //  4 MB  [BATCH,32]

    // 1) fp32 -> bf16 converts (x, l1_w, weight)
    cvt_kernel<<<18944, 256, 0, stream>>>(
        (const float4*)x, (const float4*)l1w, (const float4*)w2,
        (ushort4*)xb, (ushort4*)w1b, (ushort4*)w2b);

    // 2) h = x @ l1_w^T + l1_b   (N-fastest grid)
    gemm1_kernel<<<dim3(DHID / 128, BATCH / 128), 256, 0, stream>>>(xb, w1b, l1b, hb);

    // 3) scores = h @ weight^T + bias, fused row-max — two M-half dispatches
    gemm2_kernel<<<dim3(DOUT / 128, BATCH / 256), 256, 0, stream>>>(hb, w2b, b2, partials, 0);
    gemm2_kernel<<<dim3(DOUT / 128, BATCH / 256), 256, 0, stream>>>(hb, w2b, b2, partials, BATCH / 2);

    // 4) final max over 32 partials per row
    reduce_kernel<<<BATCH / 256, 256, 0, stream>>>((const float4*)partials, out);
}

// Round 8
// 340.060 us; speedup vs baseline: 1.4143x; 1.4143x over previous
//
#include <hip/hip_runtime.h>
#include <hip/hip_bf16.h>
#include <stdint.h>

// Problem sizes (compile-time)
static constexpr int BATCH = 32768;
static constexpr int DIN   = 512;
static constexpr int DHID  = 1024;
static constexpr int DOUT  = 2048;

typedef __bf16 bf16x8 __attribute__((ext_vector_type(8)));
typedef float  f32x4  __attribute__((ext_vector_type(4)));

// fp32 -> bf16 round-to-nearest-even
__device__ __forceinline__ unsigned short f2bf(float f) {
    unsigned int u = __float_as_uint(f);
    u += 0x7FFFu + ((u >> 16) & 1u);
    return (unsigned short)(u >> 16);
}

// async global->LDS, 16B per lane. LDS dest = wave-uniform base + 16*lane.
__device__ __forceinline__ void gload_lds16(const void* g, void* l) {
    __builtin_amdgcn_global_load_lds((__attribute__((address_space(1))) void*)g,
                                     (__attribute__((address_space(3))) void*)l,
                                     16, 0, 0);
}

// ---------------------------------------------------------------------------
// Kernel 1: convert l1_w, weight fp32 -> bf16 (x converted inside gemm1)
// ---------------------------------------------------------------------------
__global__ __launch_bounds__(256) void cvt_kernel(
    const float4* __restrict__ w1, const float4* __restrict__ w2,
    ushort4* __restrict__ w1b, ushort4* __restrict__ w2b) {
    const size_t NW1 = (size_t)DHID * DIN  / 4;   // 131,072
    const size_t NW2 = (size_t)DOUT * DHID / 4;   // 524,288
    size_t g = (size_t)blockIdx.x * blockDim.x + threadIdx.x;
    const float4* s; ushort4* d; size_t i;
    if (g < NW1)            { s = w1; d = w1b; i = g; }
    else if (g < NW1 + NW2) { s = w2; d = w2b; i = g - NW1; }
    else return;
    float4 v = s[i];
    ushort4 o;
    o.x = f2bf(v.x); o.y = f2bf(v.y); o.z = f2bf(v.z); o.w = f2bf(v.w);
    d[i] = o;
}

// ===========================================================================
// Swizzled LDS tiles (both GEMMs): 128 rows x 64 bf16 = 8 chunks(16B)/row,
//   slot(row, chunk) = row*8 + (chunk ^ (row&7)).
// async staging chunk key (lane&7)^((lane>>3)&7) is issue-independent.
// Fragment read chunk = (ks*4+q) ^ (r&7) -> measured 0 bank conflicts (r5/r6).
// Grid N-fastest for A-tile L2 sharing. B through LDS ALWAYS (r7 lesson:
// direct fragment-layout global loads issue 16 scattered 64B segs/instr).
// ===========================================================================

// ---------------------------------------------------------------------------
// GEMM1: h = x(fp32) * l1_w^T + l1_b, bf16 out. BM=128, BN=128, BK=64.
// A staged from fp32 with inline convert (VGPR roundtrip: float4 x2 ->
// cvt -> ds_write_b128 into swizzled slots). B staged async (bf16 weights).
// ---------------------------------------------------------------------------
__global__ __launch_bounds__(256) void gemm1_kernel(
    const float* __restrict__ X,            // x fp32 [BATCH, DIN]
    const unsigned short* __restrict__ Bw,  // l1_w bf16 [DHID, DIN]
    const float* __restrict__ l1b,          // [DHID]
    unsigned short* __restrict__ H) {       // out bf16 [BATCH, DHID]
    constexpr int K = DIN;
    __shared__ __align__(16) unsigned short sA[128 * 64];  // 16 KB
    __shared__ __align__(16) unsigned short sB[128 * 64];  // 16 KB

    const int tid  = threadIdx.x;
    const int lane = tid & 63;
    const int wid  = tid >> 6;
    const int wr = wid >> 1, wc = wid & 1;
    const int r = lane & 15, q = lane >> 4;
    const int sw = r & 7;
    const int blockN = blockIdx.x * 128;   // N-fastest
    const int blockM = blockIdx.y * 128;

    // A staging (fp32 -> bf16): 4 units/thread; unit u = j*256+tid:
    //   row = u>>3, ch = u&7; loads 32B fp32, writes 16B bf16 to swizzled slot.
    int aRow[4], aCh[4], aSlot[4];
#pragma unroll
    for (int j = 0; j < 4; ++j) {
        const int u   = j * 256 + tid;
        aRow[j]  = u >> 3;
        aCh[j]   = u & 7;
        aSlot[j] = aRow[j] * 8 + (aCh[j] ^ (aRow[j] & 7));
    }
    // B staging (async): 4 issues/thread
    const int chKey = (lane & 7) ^ ((lane >> 3) & 7);
    const size_t bBase = (size_t)(blockN + wid * 32 + (lane >> 3)) * K + chKey * 8;

    f32x4 acc[4][4];
#pragma unroll
    for (int mt = 0; mt < 4; ++mt)
#pragma unroll
        for (int nt = 0; nt < 4; ++nt) { f32x4 z = {0.f, 0.f, 0.f, 0.f}; acc[mt][nt] = z; }

    for (int k0 = 0; k0 < K; k0 += 64) {
        // B: async global->LDS
#pragma unroll
        for (int j = 0; j < 4; ++j)
            gload_lds16(Bw + bBase + (size_t)j * 8 * K + k0, sB + wid * 2048 + j * 512);
        // A: fp32 load + convert + ds_write
#pragma unroll
        for (int j = 0; j < 4; ++j) {
            const float* src = X + (size_t)(blockM + aRow[j]) * K + k0 + aCh[j] * 8;
            f32x4 f0 = *(const f32x4*)src;
            f32x4 f1 = *(const f32x4*)(src + 4);
            bf16x8 v;
#pragma unroll
            for (int i = 0; i < 4; ++i) { v[i] = (__bf16)f0[i]; v[4 + i] = (__bf16)f1[i]; }
            *(bf16x8*)&sA[aSlot[j] * 8] = v;
        }
        __syncthreads();
#pragma unroll
        for (int ks = 0; ks < 2; ++ks) {
            const int ch = ((ks << 2) + q) ^ sw;
            bf16x8 af[4], bf[4];
#pragma unroll
            for (int mt = 0; mt < 4; ++mt) af[mt] = *(const bf16x8*)&sA[(wr * 64 + mt * 16 + r) * 64 + ch * 8];
#pragma unroll
            for (int nt = 0; nt < 4; ++nt) bf[nt] = *(const bf16x8*)&sB[(wc * 64 + nt * 16 + r) * 64 + ch * 8];
#pragma unroll
            for (int mt = 0; mt < 4; ++mt)
#pragma unroll
                for (int nt = 0; nt < 4; ++nt)
                    acc[mt][nt] = __builtin_amdgcn_mfma_f32_16x16x32_bf16(af[mt], bf[nt], acc[mt][nt], 0, 0, 0);
        }
        __syncthreads();
    }

    // Epilogue: +bias, convert, store. C/D: col = lane&15, row = q*4+reg.
    const int colBase = blockN + wc * 64;
    const int rowBase = blockM + wr * 64;
    float bv[4];
#pragma unroll
    for (int nt = 0; nt < 4; ++nt) bv[nt] = l1b[colBase + nt * 16 + r];
#pragma unroll
    for (int mt = 0; mt < 4; ++mt) {
        const int row0 = rowBase + mt * 16 + q * 4;
#pragma unroll
        for (int nt = 0; nt < 4; ++nt) {
            const int col = colBase + nt * 16 + r;
#pragma unroll
            for (int reg = 0; reg < 4; ++reg)
                H[(size_t)(row0 + reg) * DHID + col] = f2bf(acc[mt][nt][reg] + bv[nt]);
        }
    }
}

// ---------------------------------------------------------------------------
// GEMM2: scores = H * weight^T + bias, fused row-max. 128x128, BK=64.
// Both operands async-staged (r6 structure, measured best). Two M-halves.
// ---------------------------------------------------------------------------
__global__ __launch_bounds__(256) void gemm2_kernel(
    const unsigned short* __restrict__ A,   // H bf16 [BATCH, DHID]
    const unsigned short* __restrict__ Bw,  // weight bf16 [DOUT, DHID]
    const float* __restrict__ bias,         // [DOUT]
    float* __restrict__ partials,           // [BATCH, 32]
    int mBase) {
    constexpr int K = DHID;
    __shared__ __align__(16) unsigned short sA[128 * 64];
    __shared__ __align__(16) unsigned short sB[128 * 64];

    const int tid  = threadIdx.x;
    const int lane = tid & 63;
    const int wid  = tid >> 6;
    const int wr = wid >> 1, wc = wid & 1;
    const int r = lane & 15, q = lane >> 4;
    const int sw = r & 7;
    const int blockN = blockIdx.x * 128;   // N-fastest
    const int blockM = mBase + blockIdx.y * 128;

    const int chKey = (lane & 7) ^ ((lane >> 3) & 7);
    const size_t aBase = (size_t)(blockM + wid * 32 + (lane >> 3)) * K + chKey * 8;
    const size_t bBase = (size_t)(blockN + wid * 32 + (lane >> 3)) * K + chKey * 8;

    f32x4 acc[4][4];
#pragma unroll
    for (int mt = 0; mt < 4; ++mt)
#pragma unroll
        for (int nt = 0; nt < 4; ++nt) { f32x4 z = {0.f, 0.f, 0.f, 0.f}; acc[mt][nt] = z; }

    for (int k0 = 0; k0 < K; k0 += 64) {
#pragma unroll
        for (int j = 0; j < 4; ++j) {
            gload_lds16(A  + aBase + (size_t)j * 8 * K + k0, sA + wid * 2048 + j * 512);
            gload_lds16(Bw + bBase + (size_t)j * 8 * K + k0, sB + wid * 2048 + j * 512);
        }
        __syncthreads();
#pragma unroll
        for (int ks = 0; ks < 2; ++ks) {
            const int ch = ((ks << 2) + q) ^ sw;
            bf16x8 af[4], bf[4];
#pragma unroll
            for (int mt = 0; mt < 4; ++mt) af[mt] = *(const bf16x8*)&sA[(wr * 64 + mt * 16 + r) * 64 + ch * 8];
#pragma unroll
            for (int nt = 0; nt < 4; ++nt) bf[nt] = *(const bf16x8*)&sB[(wc * 64 + nt * 16 + r) * 64 + ch * 8];
#pragma unroll
            for (int mt = 0; mt < 4; ++mt)
#pragma unroll
                for (int nt = 0; nt < 4; ++nt)
                    acc[mt][nt] = __builtin_amdgcn_mfma_f32_16x16x32_bf16(af[mt], bf[nt], acc[mt][nt], 0, 0, 0);
        }
        __syncthreads();
    }

    // Epilogue: +bias, max over the wave's 64 cols, 16-lane reduce, write partial.
    const int colBase = blockN + wc * 64;
    const int rowBase = blockM + wr * 64;
    float bv[4];
#pragma unroll
    for (int nt = 0; nt < 4; ++nt) bv[nt] = bias[colBase + nt * 16 + r];

    float mx[4][4];
#pragma unroll
    for (int mt = 0; mt < 4; ++mt)
#pragma unroll
        for (int reg = 0; reg < 4; ++reg) {
            float v = acc[mt][0][reg] + bv[0];
            v = fmaxf(v, acc[mt][1][reg] + bv[1]);
            v = fmaxf(v, acc[mt][2][reg] + bv[2]);
            v = fmaxf(v, acc[mt][3][reg] + bv[3]);
            mx[mt][reg] = v;
        }
#pragma unroll
    for (int off = 1; off < 16; off <<= 1)
#pragma unroll
        for (int mt = 0; mt < 4; ++mt)
#pragma unroll
            for (int reg = 0; reg < 4; ++reg)
                mx[mt][reg] = fmaxf(mx[mt][reg], __shfl_xor(mx[mt][reg], off));

    if (r == 0) {
#pragma unroll
        for (int mt = 0; mt < 4; ++mt)
#pragma unroll
            for (int reg = 0; reg < 4; ++reg) {
                const int row = rowBase + mt * 16 + q * 4 + reg;
                partials[(size_t)row * 32 + blockIdx.x * 2 + wc] = mx[mt][reg];
            }
    }
}

// ---------------------------------------------------------------------------
// Kernel 4: reduce 32 partials per row -> final max
// ---------------------------------------------------------------------------
__global__ __launch_bounds__(256) void reduce_kernel(
    const float4* __restrict__ partials, float* __restrict__ out) {
    const int row = blockIdx.x * blockDim.x + threadIdx.x;
    const float4* p = partials + (size_t)row * 8;
    float m = -INFINITY;
#pragma unroll
    for (int i = 0; i < 8; ++i) {
        float4 v = p[i];
        m = fmaxf(m, fmaxf(fmaxf(v.x, v.y), fmaxf(v.z, v.w)));
    }
    out[row] = m;
}

// ---------------------------------------------------------------------------
extern "C" void kernel_launch(void* const* d_in, const int* in_sizes, int n_in,
                              void* d_out, int out_size, void* d_ws, size_t ws_size,
                              hipStream_t stream) {
    const float* x   = (const float*)d_in[0];
    const float* l1w = (const float*)d_in[1];
    const float* l1b = (const float*)d_in[2];
    const float* w2  = (const float*)d_in[3];
    const float* b2  = (const float*)d_in[4];
    float* out = (float*)d_out;

    char* ws = (char*)d_ws;
    unsigned short* w1b = (unsigned short*)(ws);                 //  1 MB l1_w bf16
    unsigned short* w2b = (unsigned short*)(ws + 1048576);       //  4 MB weight bf16
    unsigned short* hb  = (unsigned short*)(ws + 5242880);       // 64 MB h bf16
    float* partials     = (float*)(ws + 72351744);               //  4 MB [BATCH,32]

    // 1) weight converts only (655,360 float4 groups)
    cvt_kernel<<<2560, 256, 0, stream>>>(
        (const float4*)l1w, (const float4*)w2, (ushort4*)w1b, (ushort4*)w2b);

    // 2) h = x @ l1_w^T + l1_b (x fp32 converted during staging; N-fastest)
    gemm1_kernel<<<dim3(DHID / 128, BATCH / 128), 256, 0, stream>>>(x, w1b, l1b, hb);

    // 3) scores = h @ weight^T + bias, fused row-max — two M-half dispatches
    gemm2_kernel<<<dim3(DOUT / 128, BATCH / 256), 256, 0, stream>>>(hb, w2b, b2, partials, 0);
    gemm2_kernel<<<dim3(DOUT / 128, BATCH / 256), 256, 0, stream>>>(hb, w2b, b2, partials, BATCH / 2);

    // 4) final max over 32 partials per row
    reduce_kernel<<<BATCH / 256, 256, 0, stream>>>((const float4*)partials, out);
}

// Round 9
// 321.243 us; speedup vs baseline: 1.4972x; 1.0586x over previous
//
#include <hip/hip_runtime.h>
#include <hip/hip_bf16.h>
#include <stdint.h>

// Problem sizes (compile-time)
static constexpr int BATCH = 32768;
static constexpr int DIN   = 512;
static constexpr int DHID  = 1024;
static constexpr int DOUT  = 2048;

typedef __bf16 bf16x8 __attribute__((ext_vector_type(8)));
typedef float  f32x4  __attribute__((ext_vector_type(4)));

// fp32 -> bf16 round-to-nearest-even
__device__ __forceinline__ unsigned short f2bf(float f) {
    unsigned int u = __float_as_uint(f);
    u += 0x7FFFu + ((u >> 16) & 1u);
    return (unsigned short)(u >> 16);
}

// async global->LDS, 16B per lane. LDS dest = wave-uniform base + 16*lane.
__device__ __forceinline__ void gload_lds16(const void* g, void* l) {
    __builtin_amdgcn_global_load_lds((__attribute__((address_space(1))) void*)g,
                                     (__attribute__((address_space(3))) void*)l,
                                     16, 0, 0);
}

// ---------------------------------------------------------------------------
// Kernel 1: convert l1_w, weight fp32 -> bf16 (x converted inside gemm1)
// ---------------------------------------------------------------------------
__global__ __launch_bounds__(256) void cvt_kernel(
    const float4* __restrict__ w1, const float4* __restrict__ w2,
    ushort4* __restrict__ w1b, ushort4* __restrict__ w2b) {
    const size_t NW1 = (size_t)DHID * DIN  / 4;   // 131,072
    const size_t NW2 = (size_t)DOUT * DHID / 4;   // 524,288
    size_t g = (size_t)blockIdx.x * blockDim.x + threadIdx.x;
    const float4* s; ushort4* d; size_t i;
    if (g < NW1)            { s = w1; d = w1b; i = g; }
    else if (g < NW1 + NW2) { s = w2; d = w2b; i = g - NW1; }
    else return;
    float4 v = s[i];
    ushort4 o;
    o.x = f2bf(v.x); o.y = f2bf(v.y); o.z = f2bf(v.z); o.w = f2bf(v.w);
    d[i] = o;
}

// ===========================================================================
// Swizzled LDS tiles (both GEMMs): 128 rows x 64 bf16 = 8 chunks(16B)/row,
//   slot(row, chunk) = row*8 + (chunk ^ (row&7)); 0 bank conflicts (measured).
// XCD-aware block swizzle (round 9): blocks dispatch round-robin to the 8
// XCDs (xcd = blockIdx % 8, m09). Decode g = blockIdx.x as xcd=g&7, i=g>>3
// and give each XCD a contiguous M-band with ALL its N-tiles, so the A
// (M-streamed) tile is fetched once into one XCD's L2 instead of 8 copies
// (r8 counters: gemm1 FETCH 264 MB vs 65 ideal = the 4x refetch this kills).
// B through LDS ALWAYS (r7: fragment-layout direct loads = 16 scattered
// 64B segments/instr, 2x regression).
// ===========================================================================

// ---------------------------------------------------------------------------
// GEMM1: h = x(fp32) * l1_w^T + l1_b, bf16 out. BM=128, BN=128, BK=64.
// A staged from fp32 with inline convert; B staged async (bf16 weights).
// ---------------------------------------------------------------------------
__global__ __launch_bounds__(256) void gemm1_kernel(
    const float* __restrict__ X,            // x fp32 [BATCH, DIN]
    const unsigned short* __restrict__ Bw,  // l1_w bf16 [DHID, DIN]
    const float* __restrict__ l1b,          // [DHID]
    unsigned short* __restrict__ H) {       // out bf16 [BATCH, DHID]
    constexpr int K = DIN;
    __shared__ __align__(16) unsigned short sA[128 * 64];  // 16 KB
    __shared__ __align__(16) unsigned short sB[128 * 64];  // 16 KB

    const int tid  = threadIdx.x;
    const int lane = tid & 63;
    const int wid  = tid >> 6;
    const int wr = wid >> 1, wc = wid & 1;
    const int r = lane & 15, q = lane >> 4;
    const int sw = r & 7;

    // XCD swizzle: 2048 blocks; xcd gets M-tiles [xcd*32, xcd*32+32) x all 8 N
    const int g    = blockIdx.x;
    const int xcd  = g & 7;
    const int i    = g >> 3;
    const int blockM = (xcd * 32 + (i >> 3)) * 128;
    const int blockN = (i & 7) * 128;

    // A staging (fp32 -> bf16): 4 units/thread; unit u = j*256+tid:
    //   row = u>>3, ch = u&7; loads 32B fp32, writes 16B bf16 to swizzled slot.
    int aRow[4], aCh[4], aSlot[4];
#pragma unroll
    for (int j = 0; j < 4; ++j) {
        const int u   = j * 256 + tid;
        aRow[j]  = u >> 3;
        aCh[j]   = u & 7;
        aSlot[j] = aRow[j] * 8 + (aCh[j] ^ (aRow[j] & 7));
    }
    // B staging (async): 4 issues/thread
    const int chKey = (lane & 7) ^ ((lane >> 3) & 7);
    const size_t bBase = (size_t)(blockN + wid * 32 + (lane >> 3)) * K + chKey * 8;

    f32x4 acc[4][4];
#pragma unroll
    for (int mt = 0; mt < 4; ++mt)
#pragma unroll
        for (int nt = 0; nt < 4; ++nt) { f32x4 z = {0.f, 0.f, 0.f, 0.f}; acc[mt][nt] = z; }

    for (int k0 = 0; k0 < K; k0 += 64) {
        // B: async global->LDS
#pragma unroll
        for (int j = 0; j < 4; ++j)
            gload_lds16(Bw + bBase + (size_t)j * 8 * K + k0, sB + wid * 2048 + j * 512);
        // A: fp32 load + convert + ds_write
#pragma unroll
        for (int j = 0; j < 4; ++j) {
            const float* src = X + (size_t)(blockM + aRow[j]) * K + k0 + aCh[j] * 8;
            f32x4 f0 = *(const f32x4*)src;
            f32x4 f1 = *(const f32x4*)(src + 4);
            bf16x8 v;
#pragma unroll
            for (int i2 = 0; i2 < 4; ++i2) { v[i2] = (__bf16)f0[i2]; v[4 + i2] = (__bf16)f1[i2]; }
            *(bf16x8*)&sA[aSlot[j] * 8] = v;
        }
        __syncthreads();
#pragma unroll
        for (int ks = 0; ks < 2; ++ks) {
            const int ch = ((ks << 2) + q) ^ sw;
            bf16x8 af[4], bf[4];
#pragma unroll
            for (int mt = 0; mt < 4; ++mt) af[mt] = *(const bf16x8*)&sA[(wr * 64 + mt * 16 + r) * 64 + ch * 8];
#pragma unroll
            for (int nt = 0; nt < 4; ++nt) bf[nt] = *(const bf16x8*)&sB[(wc * 64 + nt * 16 + r) * 64 + ch * 8];
#pragma unroll
            for (int mt = 0; mt < 4; ++mt)
#pragma unroll
                for (int nt = 0; nt < 4; ++nt)
                    acc[mt][nt] = __builtin_amdgcn_mfma_f32_16x16x32_bf16(af[mt], bf[nt], acc[mt][nt], 0, 0, 0);
        }
        __syncthreads();
    }

    // Epilogue: +bias, convert, store. C/D: col = lane&15, row = q*4+reg.
    const int colBase = blockN + wc * 64;
    const int rowBase = blockM + wr * 64;
    float bv[4];
#pragma unroll
    for (int nt = 0; nt < 4; ++nt) bv[nt] = l1b[colBase + nt * 16 + r];
#pragma unroll
    for (int mt = 0; mt < 4; ++mt) {
        const int row0 = rowBase + mt * 16 + q * 4;
#pragma unroll
        for (int nt = 0; nt < 4; ++nt) {
            const int col = colBase + nt * 16 + r;
#pragma unroll
            for (int reg = 0; reg < 4; ++reg)
                H[(size_t)(row0 + reg) * DHID + col] = f2bf(acc[mt][nt][reg] + bv[nt]);
        }
    }
}

// ---------------------------------------------------------------------------
// GEMM2: scores = H * weight^T + bias, fused row-max. 128x128, BK=64.
// Both operands async-staged. Two M-half dispatches, XCD-swizzled grid.
// ---------------------------------------------------------------------------
__global__ __launch_bounds__(256) void gemm2_kernel(
    const unsigned short* __restrict__ A,   // H bf16 [BATCH, DHID]
    const unsigned short* __restrict__ Bw,  // weight bf16 [DOUT, DHID]
    const float* __restrict__ bias,         // [DOUT]
    float* __restrict__ partials,           // [BATCH, 32]
    int mBase) {
    constexpr int K = DHID;
    __shared__ __align__(16) unsigned short sA[128 * 64];
    __shared__ __align__(16) unsigned short sB[128 * 64];

    const int tid  = threadIdx.x;
    const int lane = tid & 63;
    const int wid  = tid >> 6;
    const int wr = wid >> 1, wc = wid & 1;
    const int r = lane & 15, q = lane >> 4;
    const int sw = r & 7;

    // XCD swizzle: per half 2048 blocks = 128 M x 16 N;
    // xcd gets M-tiles [xcd*16, xcd*16+16) x all 16 N
    const int g    = blockIdx.x;
    const int xcd  = g & 7;
    const int i    = g >> 3;
    const int nIdx = i & 15;
    const int blockM = mBase + (xcd * 16 + (i >> 4)) * 128;
    const int blockN = nIdx * 128;

    const int chKey = (lane & 7) ^ ((lane >> 3) & 7);
    const size_t aBase = (size_t)(blockM + wid * 32 + (lane >> 3)) * K + chKey * 8;
    const size_t bBase = (size_t)(blockN + wid * 32 + (lane >> 3)) * K + chKey * 8;

    f32x4 acc[4][4];
#pragma unroll
    for (int mt = 0; mt < 4; ++mt)
#pragma unroll
        for (int nt = 0; nt < 4; ++nt) { f32x4 z = {0.f, 0.f, 0.f, 0.f}; acc[mt][nt] = z; }

    for (int k0 = 0; k0 < K; k0 += 64) {
#pragma unroll
        for (int j = 0; j < 4; ++j) {
            gload_lds16(A  + aBase + (size_t)j * 8 * K + k0, sA + wid * 2048 + j * 512);
            gload_lds16(Bw + bBase + (size_t)j * 8 * K + k0, sB + wid * 2048 + j * 512);
        }
        __syncthreads();
#pragma unroll
        for (int ks = 0; ks < 2; ++ks) {
            const int ch = ((ks << 2) + q) ^ sw;
            bf16x8 af[4], bf[4];
#pragma unroll
            for (int mt = 0; mt < 4; ++mt) af[mt] = *(const bf16x8*)&sA[(wr * 64 + mt * 16 + r) * 64 + ch * 8];
#pragma unroll
            for (int nt = 0; nt < 4; ++nt) bf[nt] = *(const bf16x8*)&sB[(wc * 64 + nt * 16 + r) * 64 + ch * 8];
#pragma unroll
            for (int mt = 0; mt < 4; ++mt)
#pragma unroll
                for (int nt = 0; nt < 4; ++nt)
                    acc[mt][nt] = __builtin_amdgcn_mfma_f32_16x16x32_bf16(af[mt], bf[nt], acc[mt][nt], 0, 0, 0);
        }
        __syncthreads();
    }

    // Epilogue: +bias, max over the wave's 64 cols, 16-lane reduce, write partial.
    const int colBase = blockN + wc * 64;
    const int rowBase = blockM + wr * 64;
    float bv[4];
#pragma unroll
    for (int nt = 0; nt < 4; ++nt) bv[nt] = bias[colBase + nt * 16 + r];

    float mx[4][4];
#pragma unroll
    for (int mt = 0; mt < 4; ++mt)
#pragma unroll
        for (int reg = 0; reg < 4; ++reg) {
            float v = acc[mt][0][reg] + bv[0];
            v = fmaxf(v, acc[mt][1][reg] + bv[1]);
            v = fmaxf(v, acc[mt][2][reg] + bv[2]);
            v = fmaxf(v, acc[mt][3][reg] + bv[3]);
            mx[mt][reg] = v;
        }
#pragma unroll
    for (int off = 1; off < 16; off <<= 1)
#pragma unroll
        for (int mt = 0; mt < 4; ++mt)
#pragma unroll
            for (int reg = 0; reg < 4; ++reg)
                mx[mt][reg] = fmaxf(mx[mt][reg], __shfl_xor(mx[mt][reg], off));

    if (r == 0) {
#pragma unroll
        for (int mt = 0; mt < 4; ++mt)
#pragma unroll
            for (int reg = 0; reg < 4; ++reg) {
                const int row = rowBase + mt * 16 + q * 4 + reg;
                partials[(size_t)row * 32 + nIdx * 2 + wc] = mx[mt][reg];
            }
    }
}

// ---------------------------------------------------------------------------
// Kernel 4: reduce 32 partials per row -> final max
// ---------------------------------------------------------------------------
__global__ __launch_bounds__(256) void reduce_kernel(
    const float4* __restrict__ partials, float* __restrict__ out) {
    const int row = blockIdx.x * blockDim.x + threadIdx.x;
    const float4* p = partials + (size_t)row * 8;
    float m = -INFINITY;
#pragma unroll
    for (int i = 0; i < 8; ++i) {
        float4 v = p[i];
        m = fmaxf(m, fmaxf(fmaxf(v.x, v.y), fmaxf(v.z, v.w)));
    }
    out[row] = m;
}

// ---------------------------------------------------------------------------
extern "C" void kernel_launch(void* const* d_in, const int* in_sizes, int n_in,
                              void* d_out, int out_size, void* d_ws, size_t ws_size,
                              hipStream_t stream) {
    const float* x   = (const float*)d_in[0];
    const float* l1w = (const float*)d_in[1];
    const float* l1b = (const float*)d_in[2];
    const float* w2  = (const float*)d_in[3];
    const float* b2  = (const float*)d_in[4];
    float* out = (float*)d_out;

    char* ws = (char*)d_ws;
    unsigned short* w1b = (unsigned short*)(ws);                 //  1 MB l1_w bf16
    unsigned short* w2b = (unsigned short*)(ws + 1048576);       //  4 MB weight bf16
    unsigned short* hb  = (unsigned short*)(ws + 5242880);       // 64 MB h bf16
    float* partials     = (float*)(ws + 72351744);               //  4 MB [BATCH,32]

    // 1) weight converts only
    cvt_kernel<<<2560, 256, 0, stream>>>(
        (const float4*)l1w, (const float4*)w2, (ushort4*)w1b, (ushort4*)w2b);

    // 2) h = x @ l1_w^T + l1_b (x fp32 converted during staging; XCD-swizzled)
    gemm1_kernel<<<2048, 256, 0, stream>>>(x, w1b, l1b, hb);

    // 3) scores = h @ weight^T + bias, fused row-max — two M-half dispatches
    gemm2_kernel<<<2048, 256, 0, stream>>>(hb, w2b, b2, partials, 0);
    gemm2_kernel<<<2048, 256, 0, stream>>>(hb, w2b, b2, partials, BATCH / 2);

    // 4) final max over 32 partials per row
    reduce_kernel<<<BATCH / 256, 256, 0, stream>>>((const float4*)partials, out);
}

// Round 10
// 218.821 us; speedup vs baseline: 2.1980x; 1.4681x over previous
//
#include <hip/hip_runtime.h>
#include <hip/hip_bf16.h>
#include <stdint.h>

// Problem sizes (compile-time)
static constexpr int BATCH = 32768;
static constexpr int DIN   = 512;
static constexpr int DHID  = 1024;
static constexpr int DOUT  = 2048;

typedef __bf16 bf16x8 __attribute__((ext_vector_type(8)));
typedef float  f32x4  __attribute__((ext_vector_type(4)));

// fp32 -> bf16 round-to-nearest-even
__device__ __forceinline__ unsigned short f2bf(float f) {
    unsigned int u = __float_as_uint(f);
    u += 0x7FFFu + ((u >> 16) & 1u);
    return (unsigned short)(u >> 16);
}

// async global->LDS, 16B per lane. LDS dest = wave-uniform base + 16*lane.
__device__ __forceinline__ void gload_lds16(const void* g, void* l) {
    __builtin_amdgcn_global_load_lds((__attribute__((address_space(1))) void*)g,
                                     (__attribute__((address_space(3))) void*)l,
                                     16, 0, 0);
}

// ===========================================================================
// ALGEBRAIC FUSION (round 10): scores = (x@w1^T + b1)@w2^T + b2
//   = x @ W^T + b'   with  W[o,i] = sum_h w2[o,h] w1[h,i]  (2048x512, 2.1 GF)
//                         b'[o]  = sum_h b1[h] w2[o,h] + b2[o]
// Kills gemm1 (34 GF + 64MB h round-trip) and 2/5 of gemm2's K-depth:
// main GEMM drops 171.8 -> 68.7 GF. Error model: ~0.01 score std -> absmax
// ~0.05 vs 0.111 threshold.
// GEMM structure = r6's measured-best (single-buffer BK=64, swizzled LDS,
// 0 bank conflicts, XCD-banded grid). B through LDS always (r7 lesson).
// ===========================================================================

// ---------------------------------------------------------------------------
// prep: blocks [0,512): w1[1024,512] fp32 -> w1t[512,1024] bf16 (transpose)
//       blocks [512,2560): w2 fp32 -> bf16 flat (2048*256 float4 groups)
// ---------------------------------------------------------------------------
__global__ __launch_bounds__(256) void prep_kernel(
    const float* __restrict__ w1, const float4* __restrict__ w2,
    unsigned short* __restrict__ w1t, ushort4* __restrict__ w2b) {
    if (blockIdx.x < 512) {
        __shared__ float tile[32][33];
        const int t     = threadIdx.x;
        const int tileI = blockIdx.x & 15;   // 16 i-tiles (DIN/32)
        const int tileH = blockIdx.x >> 4;   // 32 h-tiles (DHID/32)
        const int iBase = tileI * 32, hBase = tileH * 32;
        const int col = t & 31, rowq = t >> 5;
#pragma unroll
        for (int p = 0; p < 4; ++p) {
            const int row = p * 8 + rowq;
            tile[row][col] = w1[(size_t)(hBase + row) * DIN + iBase + col];
        }
        __syncthreads();
#pragma unroll
        for (int p = 0; p < 4; ++p) {
            const int row = p * 8 + rowq;   // i-index within tile
            w1t[(size_t)(iBase + row) * DHID + hBase + col] = f2bf(tile[col][row]);
        }
    } else {
        const size_t g = (size_t)(blockIdx.x - 512) * 256 + threadIdx.x;  // < 524288 exact
        float4 v = w2[g];
        ushort4 o;
        o.x = f2bf(v.x); o.y = f2bf(v.y); o.z = f2bf(v.z); o.w = f2bf(v.w);
        w2b[g] = o;
    }
}

// ---------------------------------------------------------------------------
// bgemv: b'[o] = sum_h b1[h]*w2[o,h] + b2[o]   (full fp32 precision)
// one wave per output; coalesced 256B row reads; shuffle reduce.
// ---------------------------------------------------------------------------
__global__ __launch_bounds__(256) void bgemv_kernel(
    const float* __restrict__ w2, const float* __restrict__ b1,
    const float* __restrict__ b2, float* __restrict__ bp) {
    const int o    = blockIdx.x * 4 + (threadIdx.x >> 6);
    const int lane = threadIdx.x & 63;
    const float* row = w2 + (size_t)o * DHID;
    float s = 0.f;
#pragma unroll
    for (int j = 0; j < 16; ++j) {
        const int h = j * 64 + lane;
        s += row[h] * b1[h];
    }
#pragma unroll
    for (int off = 1; off < 64; off <<= 1) s += __shfl_xor(s, off);
    if (lane == 0) bp[o] = s + b2[o];
}

// ---------------------------------------------------------------------------
// gemmW: W[o,i] = sum_h w2b[o,h] * w1t[i,h]. M=2048, N=512, K=1024.
// Standard r6 tile (128x128, BK=64, swizzled LDS, async staging). 64 blocks.
// ---------------------------------------------------------------------------
__global__ __launch_bounds__(256) void gemmW_kernel(
    const unsigned short* __restrict__ A,   // w2b [2048,1024]
    const unsigned short* __restrict__ Bw,  // w1t [512,1024]
    unsigned short* __restrict__ W) {       // out [2048,512] bf16
    constexpr int K = DHID;
    __shared__ __align__(16) unsigned short sA[128 * 64];
    __shared__ __align__(16) unsigned short sB[128 * 64];

    const int tid  = threadIdx.x;
    const int lane = tid & 63;
    const int wid  = tid >> 6;
    const int wr = wid >> 1, wc = wid & 1;
    const int r = lane & 15, q = lane >> 4;
    const int sw = r & 7;
    const int blockN = blockIdx.x * 128;
    const int blockM = blockIdx.y * 128;

    const int chKey = (lane & 7) ^ ((lane >> 3) & 7);
    const size_t aBase = (size_t)(blockM + wid * 32 + (lane >> 3)) * K + chKey * 8;
    const size_t bBase = (size_t)(blockN + wid * 32 + (lane >> 3)) * K + chKey * 8;

    f32x4 acc[4][4];
#pragma unroll
    for (int mt = 0; mt < 4; ++mt)
#pragma unroll
        for (int nt = 0; nt < 4; ++nt) { f32x4 z = {0.f, 0.f, 0.f, 0.f}; acc[mt][nt] = z; }

    for (int k0 = 0; k0 < K; k0 += 64) {
#pragma unroll
        for (int j = 0; j < 4; ++j) {
            gload_lds16(A  + aBase + (size_t)j * 8 * K + k0, sA + wid * 2048 + j * 512);
            gload_lds16(Bw + bBase + (size_t)j * 8 * K + k0, sB + wid * 2048 + j * 512);
        }
        __syncthreads();
#pragma unroll
        for (int ks = 0; ks < 2; ++ks) {
            const int ch = ((ks << 2) + q) ^ sw;
            bf16x8 af[4], bf[4];
#pragma unroll
            for (int mt = 0; mt < 4; ++mt) af[mt] = *(const bf16x8*)&sA[(wr * 64 + mt * 16 + r) * 64 + ch * 8];
#pragma unroll
            for (int nt = 0; nt < 4; ++nt) bf[nt] = *(const bf16x8*)&sB[(wc * 64 + nt * 16 + r) * 64 + ch * 8];
#pragma unroll
            for (int mt = 0; mt < 4; ++mt)
#pragma unroll
                for (int nt = 0; nt < 4; ++nt)
                    acc[mt][nt] = __builtin_amdgcn_mfma_f32_16x16x32_bf16(af[mt], bf[nt], acc[mt][nt], 0, 0, 0);
        }
        __syncthreads();
    }

    // store W bf16 row-major [DOUT, DIN]. C/D: col = lane&15, row = q*4+reg.
    const int colBase = blockN + wc * 64;
    const int rowBase = blockM + wr * 64;
#pragma unroll
    for (int mt = 0; mt < 4; ++mt) {
        const int row0 = rowBase + mt * 16 + q * 4;
#pragma unroll
        for (int nt = 0; nt < 4; ++nt) {
            const int col = colBase + nt * 16 + r;
#pragma unroll
            for (int reg = 0; reg < 4; ++reg)
                W[(size_t)(row0 + reg) * DIN + col] = f2bf(acc[mt][nt][reg]);
        }
    }
}

// ---------------------------------------------------------------------------
// gemmS: scores = x(fp32) @ W^T + b', fused row-max. BM=128, BN=128, BK=64,
// K=512. A staged from fp32 with inline convert (r8 path, measured neutral
// vs pre-cvt); B async. XCD-banded grid per M-half.
// ---------------------------------------------------------------------------
__global__ __launch_bounds__(256) void gemmS_kernel(
    const float* __restrict__ X,            // x fp32 [BATCH, DIN]
    const unsigned short* __restrict__ Bw,  // W bf16 [DOUT, DIN]
    const float* __restrict__ bp,           // b' [DOUT]
    float* __restrict__ partials,           // [BATCH, 32]
    int mBase) {
    constexpr int K = DIN;
    __shared__ __align__(16) unsigned short sA[128 * 64];  // 16 KB
    __shared__ __align__(16) unsigned short sB[128 * 64];  // 16 KB

    const int tid  = threadIdx.x;
    const int lane = tid & 63;
    const int wid  = tid >> 6;
    const int wr = wid >> 1, wc = wid & 1;
    const int r = lane & 15, q = lane >> 4;
    const int sw = r & 7;

    // XCD swizzle: per half 2048 blocks = 128 M x 16 N; xcd gets an M-band
    const int g    = blockIdx.x;
    const int xcd  = g & 7;
    const int i    = g >> 3;
    const int nIdx = i & 15;
    const int blockM = mBase + (xcd * 16 + (i >> 4)) * 128;
    const int blockN = nIdx * 128;

    // A staging (fp32 -> bf16): unit u = j*256+tid: row=u>>3, ch=u&7;
    // loads 32B fp32, writes 16B bf16 to swizzled slot row*8+(ch^(row&7)).
    int aRow[4], aCh[4], aSlot[4];
#pragma unroll
    for (int j = 0; j < 4; ++j) {
        const int u = j * 256 + tid;
        aRow[j]  = u >> 3;
        aCh[j]   = u & 7;
        aSlot[j] = aRow[j] * 8 + (aCh[j] ^ (aRow[j] & 7));
    }
    const int chKey = (lane & 7) ^ ((lane >> 3) & 7);
    const size_t bBase = (size_t)(blockN + wid * 32 + (lane >> 3)) * K + chKey * 8;

    f32x4 acc[4][4];
#pragma unroll
    for (int mt = 0; mt < 4; ++mt)
#pragma unroll
        for (int nt = 0; nt < 4; ++nt) { f32x4 z = {0.f, 0.f, 0.f, 0.f}; acc[mt][nt] = z; }

    for (int k0 = 0; k0 < K; k0 += 64) {
#pragma unroll
        for (int j = 0; j < 4; ++j)
            gload_lds16(Bw + bBase + (size_t)j * 8 * K + k0, sB + wid * 2048 + j * 512);
#pragma unroll
        for (int j = 0; j < 4; ++j) {
            const float* src = X + (size_t)(blockM + aRow[j]) * K + k0 + aCh[j] * 8;
            f32x4 f0 = *(const f32x4*)src;
            f32x4 f1 = *(const f32x4*)(src + 4);
            bf16x8 v;
#pragma unroll
            for (int i2 = 0; i2 < 4; ++i2) { v[i2] = (__bf16)f0[i2]; v[4 + i2] = (__bf16)f1[i2]; }
            *(bf16x8*)&sA[aSlot[j] * 8] = v;
        }
        __syncthreads();
#pragma unroll
        for (int ks = 0; ks < 2; ++ks) {
            const int ch = ((ks << 2) + q) ^ sw;
            bf16x8 af[4], bf[4];
#pragma unroll
            for (int mt = 0; mt < 4; ++mt) af[mt] = *(const bf16x8*)&sA[(wr * 64 + mt * 16 + r) * 64 + ch * 8];
#pragma unroll
            for (int nt = 0; nt < 4; ++nt) bf[nt] = *(const bf16x8*)&sB[(wc * 64 + nt * 16 + r) * 64 + ch * 8];
#pragma unroll
            for (int mt = 0; mt < 4; ++mt)
#pragma unroll
                for (int nt = 0; nt < 4; ++nt)
                    acc[mt][nt] = __builtin_amdgcn_mfma_f32_16x16x32_bf16(af[mt], bf[nt], acc[mt][nt], 0, 0, 0);
        }
        __syncthreads();
    }

    // Epilogue: +b', max over the wave's 64 cols, 16-lane reduce, write partial.
    const int colBase = blockN + wc * 64;
    const int rowBase = blockM + wr * 64;
    float bv[4];
#pragma unroll
    for (int nt = 0; nt < 4; ++nt) bv[nt] = bp[colBase + nt * 16 + r];

    float mx[4][4];
#pragma unroll
    for (int mt = 0; mt < 4; ++mt)
#pragma unroll
        for (int reg = 0; reg < 4; ++reg) {
            float v = acc[mt][0][reg] + bv[0];
            v = fmaxf(v, acc[mt][1][reg] + bv[1]);
            v = fmaxf(v, acc[mt][2][reg] + bv[2]);
            v = fmaxf(v, acc[mt][3][reg] + bv[3]);
            mx[mt][reg] = v;
        }
#pragma unroll
    for (int off = 1; off < 16; off <<= 1)
#pragma unroll
        for (int mt = 0; mt < 4; ++mt)
#pragma unroll
            for (int reg = 0; reg < 4; ++reg)
                mx[mt][reg] = fmaxf(mx[mt][reg], __shfl_xor(mx[mt][reg], off));

    if (r == 0) {
#pragma unroll
        for (int mt = 0; mt < 4; ++mt)
#pragma unroll
            for (int reg = 0; reg < 4; ++reg) {
                const int row = rowBase + mt * 16 + q * 4 + reg;
                partials[(size_t)row * 32 + nIdx * 2 + wc] = mx[mt][reg];
            }
    }
}

// ---------------------------------------------------------------------------
// reduce: 32 partials per row -> final max
// ---------------------------------------------------------------------------
__global__ __launch_bounds__(256) void reduce_kernel(
    const float4* __restrict__ partials, float* __restrict__ out) {
    const int row = blockIdx.x * blockDim.x + threadIdx.x;
    const float4* p = partials + (size_t)row * 8;
    float m = -INFINITY;
#pragma unroll
    for (int i = 0; i < 8; ++i) {
        float4 v = p[i];
        m = fmaxf(m, fmaxf(fmaxf(v.x, v.y), fmaxf(v.z, v.w)));
    }
    out[row] = m;
}

// ---------------------------------------------------------------------------
extern "C" void kernel_launch(void* const* d_in, const int* in_sizes, int n_in,
                              void* d_out, int out_size, void* d_ws, size_t ws_size,
                              hipStream_t stream) {
    const float* x   = (const float*)d_in[0];
    const float* l1w = (const float*)d_in[1];
    const float* l1b = (const float*)d_in[2];
    const float* w2  = (const float*)d_in[3];
    const float* b2  = (const float*)d_in[4];
    float* out = (float*)d_out;

    char* ws = (char*)d_ws;
    unsigned short* w1t = (unsigned short*)(ws);                 // 1 MB  w1^T bf16 [512,1024]
    unsigned short* w2b = (unsigned short*)(ws + 1048576);       // 4 MB  w2 bf16 [2048,1024]
    unsigned short* Wb  = (unsigned short*)(ws + 5242880);       // 2 MB  W bf16 [2048,512]
    float* bp           = (float*)(ws + 7340032);                // 8 KB  b' fp32 [2048]
    float* partials     = (float*)(ws + 7348224);                // 4 MB  [BATCH,32]

    // 1) w1 transpose->bf16 + w2 cvt (one dispatch)
    prep_kernel<<<2560, 256, 0, stream>>>(l1w, (const float4*)w2, w1t, (ushort4*)w2b);

    // 2) b'[o] = b1 . w2[o,:] + b2[o]  (fp32, independent of prep)
    bgemv_kernel<<<512, 256, 0, stream>>>(w2, l1b, b2, bp);

    // 3) W = w2b @ w1t^T  [2048, 512]
    gemmW_kernel<<<dim3(DIN / 128, DOUT / 128), 256, 0, stream>>>(w2b, w1t, Wb);

    // 4) scores = x @ W^T + b', fused row-max — two M-half dispatches
    gemmS_kernel<<<2048, 256, 0, stream>>>(x, Wb, bp, partials, 0);
    gemmS_kernel<<<2048, 256, 0, stream>>>(x, Wb, bp, partials, BATCH / 2);

    // 5) final max over 32 partials per row
    reduce_kernel<<<BATCH / 256, 256, 0, stream>>>((const float4*)partials, out);
}

// Round 11
// 203.626 us; speedup vs baseline: 2.3620x; 1.0746x over previous
//
#include <hip/hip_runtime.h>
#include <hip/hip_bf16.h>
#include <stdint.h>

// Problem sizes (compile-time)
static constexpr int BATCH = 32768;
static constexpr int DIN   = 512;
static constexpr int DHID  = 1024;
static constexpr int DOUT  = 2048;

typedef __bf16 bf16x8 __attribute__((ext_vector_type(8)));
typedef float  f32x4  __attribute__((ext_vector_type(4)));

// fp32 -> bf16 round-to-nearest-even
__device__ __forceinline__ unsigned short f2bf(float f) {
    unsigned int u = __float_as_uint(f);
    u += 0x7FFFu + ((u >> 16) & 1u);
    return (unsigned short)(u >> 16);
}

// async global->LDS, 16B per lane. LDS dest = wave-uniform base + 16*lane.
__device__ __forceinline__ void gload_lds16(const void* g, void* l) {
    __builtin_amdgcn_global_load_lds((__attribute__((address_space(1))) void*)g,
                                     (__attribute__((address_space(3))) void*)l,
                                     16, 0, 0);
}

// ===========================================================================
// ALGEBRAIC FUSION (r10, kept): scores = x @ W^T + b'
//   W[o,i] = sum_h w2[o,h] w1[h,i]   (2048x512; 4.3 GF to build)
//   b'[o]  = sum_h b1[h] w2[o,h] + b2[o]
// Main GEMM = 68.7 GF (vs 171.8 two-stage). r10 measured absmax 0.03125.
// r11: gemmS uses BOTH-async staging (r9: async=751 TF vs inline-cvt=374 TF),
// x pre-converted in the fused prep; gemmW re-tiled 64x64 for parallelism;
// all pre-work merged into ONE dispatch (prep+cvt+bgemv).
// LDS swizzle (verified 0 conflicts): slot(row,chunk)=row*8+(chunk^(row&7));
// staging chunk key (lane&7)^(lane>>3) is issue-independent.
// B through LDS always (r7: direct fragment loads = scattered 64B segs, 2x).
// ===========================================================================

// ---------------------------------------------------------------------------
// prep: one dispatch, region-decoded by blockIdx.x
//   [0,512)        : w1[1024,512] fp32 -> w1t[512,1024] bf16 (transpose)
//   [512,2560)     : w2 fp32 -> w2b bf16  (524288 float4 groups)
//   [2560,18944)   : x  fp32 -> xb  bf16  (4194304 float4 groups)
//   [18944,19456)  : bgemv  b'[o] = b1 . w2[o,:] + b2[o]  (fp32)
// ---------------------------------------------------------------------------
__global__ __launch_bounds__(256) void prep_kernel(
    const float* __restrict__ w1, const float4* __restrict__ w2f,
    const float4* __restrict__ xf, const float* __restrict__ b1,
    const float* __restrict__ b2,
    unsigned short* __restrict__ w1t, ushort4* __restrict__ w2b,
    ushort4* __restrict__ xb, float* __restrict__ bp) {
    const int blk = blockIdx.x;
    const int t   = threadIdx.x;
    if (blk < 512) {
        // w1 transpose -> bf16
        __shared__ float tile[32][33];
        const int tileI = blk & 15;   // 16 i-tiles (DIN/32)
        const int tileH = blk >> 4;   // 32 h-tiles (DHID/32)
        const int iBase = tileI * 32, hBase = tileH * 32;
        const int col = t & 31, rowq = t >> 5;
#pragma unroll
        for (int p = 0; p < 4; ++p) {
            const int row = p * 8 + rowq;
            tile[row][col] = w1[(size_t)(hBase + row) * DIN + iBase + col];
        }
        __syncthreads();
#pragma unroll
        for (int p = 0; p < 4; ++p) {
            const int row = p * 8 + rowq;   // i-index within tile
            w1t[(size_t)(iBase + row) * DHID + hBase + col] = f2bf(tile[col][row]);
        }
    } else if (blk < 2560) {
        const size_t g = (size_t)(blk - 512) * 256 + t;   // < 524288
        float4 v = w2f[g];
        ushort4 o;
        o.x = f2bf(v.x); o.y = f2bf(v.y); o.z = f2bf(v.z); o.w = f2bf(v.w);
        w2b[g] = o;
    } else if (blk < 18944) {
        const size_t g = (size_t)(blk - 2560) * 256 + t;  // < 4194304
        float4 v = xf[g];
        ushort4 o;
        o.x = f2bf(v.x); o.y = f2bf(v.y); o.z = f2bf(v.z); o.w = f2bf(v.w);
        xb[g] = o;
    } else {
        // bgemv: one wave per output o
        const int o    = (blk - 18944) * 4 + (t >> 6);
        const int lane = t & 63;
        const float* row = (const float*)w2f + (size_t)o * DHID;
        float s = 0.f;
#pragma unroll
        for (int j = 0; j < 16; ++j) {
            const int h = j * 64 + lane;
            s += row[h] * b1[h];
        }
#pragma unroll
        for (int off = 1; off < 64; off <<= 1) s += __shfl_xor(s, off);
        if (lane == 0) bp[o] = s + b2[o];
    }
}

// ---------------------------------------------------------------------------
// gemmW: W[o,i] = sum_h w2b[o,h] * w1t[i,h]. M=2048, N=512, K=1024.
// 64x64 tiles -> 256 blocks (parallelism; r10's 64-block grid used 1/4 chip).
// 4 waves 2x2; wave = 32x32 via 2x2 mfma_16x16x32. BK=64.
// ---------------------------------------------------------------------------
__global__ __launch_bounds__(256) void gemmW_kernel(
    const unsigned short* __restrict__ A,   // w2b [2048,1024]
    const unsigned short* __restrict__ Bw,  // w1t [512,1024]
    unsigned short* __restrict__ W) {       // out [2048,512] bf16
    constexpr int K = DHID;
    __shared__ __align__(16) unsigned short sA[64 * 64];  // 8 KB
    __shared__ __align__(16) unsigned short sB[64 * 64];  // 8 KB

    const int tid  = threadIdx.x;
    const int lane = tid & 63;
    const int wid  = tid >> 6;
    const int wr = wid >> 1, wc = wid & 1;
    const int r = lane & 15, q = lane >> 4;
    const int sw = r & 7;
    const int blockN = blockIdx.x * 64;   // 8
    const int blockM = blockIdx.y * 64;   // 32

    const int chKey = (lane & 7) ^ (lane >> 3);
    // rows advance 8 per j (row = j*32 + wid*8 + (lane>>3)); row&7 = lane>>3
    const size_t aBase = (size_t)(blockM + wid * 8 + (lane >> 3)) * K + chKey * 8;
    const size_t bBase = (size_t)(blockN + wid * 8 + (lane >> 3)) * K + chKey * 8;

    f32x4 acc[2][2];
#pragma unroll
    for (int mt = 0; mt < 2; ++mt)
#pragma unroll
        for (int nt = 0; nt < 2; ++nt) { f32x4 z = {0.f, 0.f, 0.f, 0.f}; acc[mt][nt] = z; }

    for (int k0 = 0; k0 < K; k0 += 64) {
#pragma unroll
        for (int j = 0; j < 2; ++j) {
            gload_lds16(A  + aBase + (size_t)j * 32 * K + k0, sA + j * 2048 + wid * 512);
            gload_lds16(Bw + bBase + (size_t)j * 32 * K + k0, sB + j * 2048 + wid * 512);
        }
        __syncthreads();
#pragma unroll
        for (int ks = 0; ks < 2; ++ks) {
            const int ch = ((ks << 2) + q) ^ sw;
            bf16x8 af[2], bf[2];
#pragma unroll
            for (int mt = 0; mt < 2; ++mt) af[mt] = *(const bf16x8*)&sA[(wr * 32 + mt * 16 + r) * 64 + ch * 8];
#pragma unroll
            for (int nt = 0; nt < 2; ++nt) bf[nt] = *(const bf16x8*)&sB[(wc * 32 + nt * 16 + r) * 64 + ch * 8];
#pragma unroll
            for (int mt = 0; mt < 2; ++mt)
#pragma unroll
                for (int nt = 0; nt < 2; ++nt)
                    acc[mt][nt] = __builtin_amdgcn_mfma_f32_16x16x32_bf16(af[mt], bf[nt], acc[mt][nt], 0, 0, 0);
        }
        __syncthreads();
    }

    // store W bf16 [DOUT, DIN]. C/D: col = lane&15, row = q*4+reg.
#pragma unroll
    for (int mt = 0; mt < 2; ++mt) {
        const int row0 = blockM + wr * 32 + mt * 16 + q * 4;
#pragma unroll
        for (int nt = 0; nt < 2; ++nt) {
            const int col = blockN + wc * 32 + nt * 16 + r;
#pragma unroll
            for (int reg = 0; reg < 4; ++reg)
                W[(size_t)(row0 + reg) * DIN + col] = f2bf(acc[mt][nt][reg]);
        }
    }
}

// ---------------------------------------------------------------------------
// gemmS: scores = xb @ W^T + b', fused row-max. BM=128, BN=128, BK=64, K=512.
// Both operands async-staged (r9-measured best: 751 TF). One 4096-block
// dispatch, XCD-banded: xcd gets M-tiles [xcd*32, xcd*32+32) x all 16 N.
// ---------------------------------------------------------------------------
__global__ __launch_bounds__(256) void gemmS_kernel(
    const unsigned short* __restrict__ A,   // xb bf16 [BATCH, DIN]
    const unsigned short* __restrict__ Bw,  // W bf16 [DOUT, DIN]
    const float* __restrict__ bp,           // b' [DOUT]
    float* __restrict__ partials) {         // [BATCH, 32]
    constexpr int K = DIN;
    __shared__ __align__(16) unsigned short sA[128 * 64];  // 16 KB
    __shared__ __align__(16) unsigned short sB[128 * 64];  // 16 KB

    const int tid  = threadIdx.x;
    const int lane = tid & 63;
    const int wid  = tid >> 6;
    const int wr = wid >> 1, wc = wid & 1;
    const int r = lane & 15, q = lane >> 4;
    const int sw = r & 7;

    // XCD band: 4096 blocks = 8 xcd x (32 M x 16 N)
    const int g    = blockIdx.x;
    const int xcd  = g & 7;
    const int i    = g >> 3;
    const int nIdx = i & 15;
    const int blockM = (xcd * 32 + (i >> 4)) * 128;
    const int blockN = nIdx * 128;

    const int chKey = (lane & 7) ^ (lane >> 3);
    const size_t aBase = (size_t)(blockM + wid * 32 + (lane >> 3)) * K + chKey * 8;
    const size_t bBase = (size_t)(blockN + wid * 32 + (lane >> 3)) * K + chKey * 8;

    f32x4 acc[4][4];
#pragma unroll
    for (int mt = 0; mt < 4; ++mt)
#pragma unroll
        for (int nt = 0; nt < 4; ++nt) { f32x4 z = {0.f, 0.f, 0.f, 0.f}; acc[mt][nt] = z; }

    for (int k0 = 0; k0 < K; k0 += 64) {
#pragma unroll
        for (int j = 0; j < 4; ++j) {
            gload_lds16(A  + aBase + (size_t)j * 8 * K + k0, sA + wid * 2048 + j * 512);
            gload_lds16(Bw + bBase + (size_t)j * 8 * K + k0, sB + wid * 2048 + j * 512);
        }
        __syncthreads();
#pragma unroll
        for (int ks = 0; ks < 2; ++ks) {
            const int ch = ((ks << 2) + q) ^ sw;
            bf16x8 af[4], bf[4];
#pragma unroll
            for (int mt = 0; mt < 4; ++mt) af[mt] = *(const bf16x8*)&sA[(wr * 64 + mt * 16 + r) * 64 + ch * 8];
#pragma unroll
            for (int nt = 0; nt < 4; ++nt) bf[nt] = *(const bf16x8*)&sB[(wc * 64 + nt * 16 + r) * 64 + ch * 8];
#pragma unroll
            for (int mt = 0; mt < 4; ++mt)
#pragma unroll
                for (int nt = 0; nt < 4; ++nt)
                    acc[mt][nt] = __builtin_amdgcn_mfma_f32_16x16x32_bf16(af[mt], bf[nt], acc[mt][nt], 0, 0, 0);
        }
        __syncthreads();
    }

    // Epilogue: +b', max over the wave's 64 cols, 16-lane reduce, write partial.
    const int colBase = blockN + wc * 64;
    const int rowBase = blockM + wr * 64;
    float bv[4];
#pragma unroll
    for (int nt = 0; nt < 4; ++nt) bv[nt] = bp[colBase + nt * 16 + r];

    float mx[4][4];
#pragma unroll
    for (int mt = 0; mt < 4; ++mt)
#pragma unroll
        for (int reg = 0; reg < 4; ++reg) {
            float v = acc[mt][0][reg] + bv[0];
            v = fmaxf(v, acc[mt][1][reg] + bv[1]);
            v = fmaxf(v, acc[mt][2][reg] + bv[2]);
            v = fmaxf(v, acc[mt][3][reg] + bv[3]);
            mx[mt][reg] = v;
        }
#pragma unroll
    for (int off = 1; off < 16; off <<= 1)
#pragma unroll
        for (int mt = 0; mt < 4; ++mt)
#pragma unroll
            for (int reg = 0; reg < 4; ++reg)
                mx[mt][reg] = fmaxf(mx[mt][reg], __shfl_xor(mx[mt][reg], off));

    if (r == 0) {
#pragma unroll
        for (int mt = 0; mt < 4; ++mt)
#pragma unroll
            for (int reg = 0; reg < 4; ++reg) {
                const int row = rowBase + mt * 16 + q * 4 + reg;
                partials[(size_t)row * 32 + nIdx * 2 + wc] = mx[mt][reg];
            }
    }
}

// ---------------------------------------------------------------------------
// reduce: 32 partials per row -> final max
// ---------------------------------------------------------------------------
__global__ __launch_bounds__(256) void reduce_kernel(
    const float4* __restrict__ partials, float* __restrict__ out) {
    const int row = blockIdx.x * blockDim.x + threadIdx.x;
    const float4* p = partials + (size_t)row * 8;
    float m = -INFINITY;
#pragma unroll
    for (int i = 0; i < 8; ++i) {
        float4 v = p[i];
        m = fmaxf(m, fmaxf(fmaxf(v.x, v.y), fmaxf(v.z, v.w)));
    }
    out[row] = m;
}

// ---------------------------------------------------------------------------
extern "C" void kernel_launch(void* const* d_in, const int* in_sizes, int n_in,
                              void* d_out, int out_size, void* d_ws, size_t ws_size,
                              hipStream_t stream) {
    const float* x   = (const float*)d_in[0];
    const float* l1w = (const float*)d_in[1];
    const float* l1b = (const float*)d_in[2];
    const float* w2  = (const float*)d_in[3];
    const float* b2  = (const float*)d_in[4];
    float* out = (float*)d_out;

    char* ws = (char*)d_ws;
    unsigned short* w1t = (unsigned short*)(ws);                 //  1 MB  w1^T bf16 [512,1024]
    unsigned short* w2b = (unsigned short*)(ws + 1048576);       //  4 MB  w2 bf16 [2048,1024]
    unsigned short* Wb  = (unsigned short*)(ws + 5242880);       //  2 MB  W bf16 [2048,512]
    float* bp           = (float*)(ws + 7340032);                //  8 KB  b' fp32 [2048]
    unsigned short* xb  = (unsigned short*)(ws + 7348224);       // 32 MB  x bf16 [32768,512]
    float* partials     = (float*)(ws + 40902656);               //  4 MB  [BATCH,32]

    // 1) fused pre-work: w1 transpose + w2 cvt + x cvt + b' gemv
    prep_kernel<<<19456, 256, 0, stream>>>(
        l1w, (const float4*)w2, (const float4*)x, l1b, b2,
        w1t, (ushort4*)w2b, (ushort4*)xb, bp);

    // 2) W = w2b @ w1t^T  [2048, 512]  (256 blocks)
    gemmW_kernel<<<dim3(DIN / 64, DOUT / 64), 256, 0, stream>>>(w2b, w1t, Wb);

    // 3) scores = xb @ W^T + b', fused row-max (one 4096-block dispatch)
    gemmS_kernel<<<4096, 256, 0, stream>>>(xb, Wb, bp, partials);

    // 4) final max over 32 partials per row
    reduce_kernel<<<BATCH / 256, 256, 0, stream>>>((const float4*)partials, out);
}

// Round 14
// 201.177 us; speedup vs baseline: 2.3907x; 1.0122x over previous
//
#include <hip/hip_runtime.h>
#include <hip/hip_bf16.h>
#include <stdint.h>

// Problem sizes (compile-time)
static constexpr int BATCH = 32768;
static constexpr int DIN   = 512;
static constexpr int DHID  = 1024;
static constexpr int DOUT  = 2048;

typedef __bf16 bf16x8 __attribute__((ext_vector_type(8)));
typedef float  f32x4  __attribute__((ext_vector_type(4)));

// fp32 -> bf16 round-to-nearest-even
__device__ __forceinline__ unsigned short f2bf(float f) {
    unsigned int u = __float_as_uint(f);
    u += 0x7FFFu + ((u >> 16) & 1u);
    return (unsigned short)(u >> 16);
}

// async global->LDS, 16B per lane. LDS dest = WAVE-uniform base + 16*(lane&63).
// r13 bug: forgot the wid term in the base -> 4 waves raced one LDS quarter.
__device__ __forceinline__ void gload_lds16(const void* g, void* l) {
    __builtin_amdgcn_global_load_lds((__attribute__((address_space(1))) void*)g,
                                     (__attribute__((address_space(3))) void*)l,
                                     16, 0, 0);
}

// ===========================================================================
// scores = x @ W^T + b' (algebraic fusion, r10; absmax 0.03125 measured)
//   W[o,i] = sum_h w2[o,h] w1[h,i];  b'[o] = dot(b1, w2[o,:]) + b2[o]
// Single stream only (r12: hipEvent*/multi-stream breaks graph capture).
// r14 = r13 with the gemmW LDS-base fix (+ wid*512 per issue).
// ===========================================================================

// ---------------------------------------------------------------------------
// prep: one dispatch, region-decoded by blockIdx.x
//   [0,512)        : w1[1024,512] fp32 -> w1t[512,1024] bf16 (transpose)
//   [512,2560)     : w2 row o=blk-512: cvt to bf16 + bp[o]=dot(b1,row)+b2[o]
//   [2560,18944)   : x fp32 -> bf16  (4194304 float4 groups)
// ---------------------------------------------------------------------------
__global__ __launch_bounds__(256) void prep_kernel(
    const float* __restrict__ w1, const float4* __restrict__ w2f,
    const float4* __restrict__ xf, const float* __restrict__ b1,
    const float* __restrict__ b2,
    unsigned short* __restrict__ w1t, ushort4* __restrict__ w2b,
    ushort4* __restrict__ xb, float* __restrict__ bp) {
    const int blk = blockIdx.x;
    const int t   = threadIdx.x;
    if (blk < 512) {
        // w1 transpose -> bf16
        __shared__ float tile[32][33];
        const int tileI = blk & 15;   // 16 i-tiles (DIN/32)
        const int tileH = blk >> 4;   // 32 h-tiles (DHID/32)
        const int iBase = tileI * 32, hBase = tileH * 32;
        const int col = t & 31, rowq = t >> 5;
#pragma unroll
        for (int p = 0; p < 4; ++p) {
            const int row = p * 8 + rowq;
            tile[row][col] = w1[(size_t)(hBase + row) * DIN + iBase + col];
        }
        __syncthreads();
#pragma unroll
        for (int p = 0; p < 4; ++p) {
            const int row = p * 8 + rowq;   // i-index within tile
            w1t[(size_t)(iBase + row) * DHID + hBase + col] = f2bf(tile[col][row]);
        }
    } else if (blk < 2560) {
        // one block per w2 row: cvt + fused bgemv
        __shared__ float wsum[4];
        const int o = blk - 512;
        const size_t g = (size_t)o * 256 + t;
        float4 v = w2f[g];
        ushort4 ob;
        ob.x = f2bf(v.x); ob.y = f2bf(v.y); ob.z = f2bf(v.z); ob.w = f2bf(v.w);
        w2b[g] = ob;
        float4 bv = ((const float4*)b1)[t];
        float s = v.x * bv.x + v.y * bv.y + v.z * bv.z + v.w * bv.w;
#pragma unroll
        for (int off = 1; off < 64; off <<= 1) s += __shfl_xor(s, off);
        if ((t & 63) == 0) wsum[t >> 6] = s;
        __syncthreads();
        if (t == 0) bp[o] = wsum[0] + wsum[1] + wsum[2] + wsum[3] + b2[o];
    } else {
        const size_t g = (size_t)(blk - 2560) * 256 + t;  // < 4194304
        float4 v = xf[g];
        ushort4 o;
        o.x = f2bf(v.x); o.y = f2bf(v.y); o.z = f2bf(v.z); o.w = f2bf(v.w);
        xb[g] = o;
    }
}

// ---------------------------------------------------------------------------
// gemmW: W[o,i] = sum_h w2b[o,h] * w1t[i,h]. M=2048, N=512, K=1024.
// 64x64 tiles (256 blocks), BK=128 (8 iters). LDS 64 rows x 128 bf16 =
// 16 chunks/row, swizzled slot(row,chunk) = row*16 + (chunk ^ (row&15)).
// Staging slot s = j*256 + wid*64 + lane -> LDS base sA + j*2048 + wid*512
// (the r13 bug was the missing wid*512). Global: row = s>>4 = tid>>4 + j*16,
// chunk = (s&15) ^ (row&15) -> chKey = (tid&15)^((tid>>4)&15), issue-indep.
// Fragment read ch = (ks*4+q) ^ r  (fragment row&15 == r).
// ---------------------------------------------------------------------------
__global__ __launch_bounds__(256) void gemmW_kernel(
    const unsigned short* __restrict__ A,   // w2b [2048,1024]
    const unsigned short* __restrict__ Bw,  // w1t [512,1024]
    unsigned short* __restrict__ W) {       // out [2048,512] bf16
    constexpr int K = DHID;
    __shared__ __align__(16) unsigned short sA[64 * 128];  // 16 KB
    __shared__ __align__(16) unsigned short sB[64 * 128];  // 16 KB

    const int tid  = threadIdx.x;
    const int lane = tid & 63;
    const int wid  = tid >> 6;
    const int wr = wid >> 1, wc = wid & 1;
    const int r = lane & 15, q = lane >> 4;
    const int blockN = blockIdx.x * 64;   // 8
    const int blockM = blockIdx.y * 64;   // 32

    const int chKey = (tid & 15) ^ ((tid >> 4) & 15);
    const size_t aBase = (size_t)(blockM + (tid >> 4)) * K + chKey * 8;
    const size_t bBase = (size_t)(blockN + (tid >> 4)) * K + chKey * 8;

    f32x4 acc[2][2];
#pragma unroll
    for (int mt = 0; mt < 2; ++mt)
#pragma unroll
        for (int nt = 0; nt < 2; ++nt) { f32x4 z = {0.f, 0.f, 0.f, 0.f}; acc[mt][nt] = z; }

    for (int k0 = 0; k0 < K; k0 += 128) {
#pragma unroll
        for (int j = 0; j < 4; ++j) {
            gload_lds16(A  + aBase + (size_t)j * 16 * K + k0, sA + j * 2048 + wid * 512);
            gload_lds16(Bw + bBase + (size_t)j * 16 * K + k0, sB + j * 2048 + wid * 512);
        }
        __syncthreads();
#pragma unroll
        for (int ks = 0; ks < 4; ++ks) {
            const int ch = ((ks << 2) + q) ^ r;
            bf16x8 af[2], bf[2];
#pragma unroll
            for (int mt = 0; mt < 2; ++mt) af[mt] = *(const bf16x8*)&sA[(wr * 32 + mt * 16 + r) * 128 + ch * 8];
#pragma unroll
            for (int nt = 0; nt < 2; ++nt) bf[nt] = *(const bf16x8*)&sB[(wc * 32 + nt * 16 + r) * 128 + ch * 8];
#pragma unroll
            for (int mt = 0; mt < 2; ++mt)
#pragma unroll
                for (int nt = 0; nt < 2; ++nt)
                    acc[mt][nt] = __builtin_amdgcn_mfma_f32_16x16x32_bf16(af[mt], bf[nt], acc[mt][nt], 0, 0, 0);
        }
        __syncthreads();
    }

    // store W bf16 [DOUT, DIN]. C/D: col = lane&15, row = q*4+reg.
#pragma unroll
    for (int mt = 0; mt < 2; ++mt) {
        const int row0 = blockM + wr * 32 + mt * 16 + q * 4;
#pragma unroll
        for (int nt = 0; nt < 2; ++nt) {
            const int col = blockN + wc * 32 + nt * 16 + r;
#pragma unroll
            for (int reg = 0; reg < 4; ++reg)
                W[(size_t)(row0 + reg) * DIN + col] = f2bf(acc[mt][nt][reg]);
        }
    }
}

// ---------------------------------------------------------------------------
// gemmS: scores = xb @ W^T + b', fused row-max. BM=128, BN=128, BK=64, K=512.
// Both-async staging (measured 750 TF). One 4096-block XCD-banded grid.
// ---------------------------------------------------------------------------
__global__ __launch_bounds__(256) void gemmS_kernel(
    const unsigned short* __restrict__ A,   // xb bf16 [BATCH, DIN]
    const unsigned short* __restrict__ Bw,  // W bf16 [DOUT, DIN]
    const float* __restrict__ bp,           // b' [DOUT]
    float* __restrict__ partials) {         // [BATCH, 32]
    constexpr int K = DIN;
    __shared__ __align__(16) unsigned short sA[128 * 64];  // 16 KB
    __shared__ __align__(16) unsigned short sB[128 * 64];  // 16 KB

    const int tid  = threadIdx.x;
    const int lane = tid & 63;
    const int wid  = tid >> 6;
    const int wr = wid >> 1, wc = wid & 1;
    const int r = lane & 15, q = lane >> 4;
    const int sw = r & 7;

    // XCD band: 4096 blocks = 8 xcd x (32 M x 16 N)
    const int g    = blockIdx.x;
    const int xcd  = g & 7;
    const int i    = g >> 3;
    const int nIdx = i & 15;
    const int blockM = (xcd * 32 + (i >> 4)) * 128;
    const int blockN = nIdx * 128;

    const int chKey = (lane & 7) ^ (lane >> 3);
    const size_t aBase = (size_t)(blockM + wid * 32 + (lane >> 3)) * K + chKey * 8;
    const size_t bBase = (size_t)(blockN + wid * 32 + (lane >> 3)) * K + chKey * 8;

    f32x4 acc[4][4];
#pragma unroll
    for (int mt = 0; mt < 4; ++mt)
#pragma unroll
        for (int nt = 0; nt < 4; ++nt) { f32x4 z = {0.f, 0.f, 0.f, 0.f}; acc[mt][nt] = z; }

    for (int k0 = 0; k0 < K; k0 += 64) {
#pragma unroll
        for (int j = 0; j < 4; ++j) {
            gload_lds16(A  + aBase + (size_t)j * 8 * K + k0, sA + wid * 2048 + j * 512);
            gload_lds16(Bw + bBase + (size_t)j * 8 * K + k0, sB + wid * 2048 + j * 512);
        }
        __syncthreads();
#pragma unroll
        for (int ks = 0; ks < 2; ++ks) {
            const int ch = ((ks << 2) + q) ^ sw;
            bf16x8 af[4], bf[4];
#pragma unroll
            for (int mt = 0; mt < 4; ++mt) af[mt] = *(const bf16x8*)&sA[(wr * 64 + mt * 16 + r) * 64 + ch * 8];
#pragma unroll
            for (int nt = 0; nt < 4; ++nt) bf[nt] = *(const bf16x8*)&sB[(wc * 64 + nt * 16 + r) * 64 + ch * 8];
#pragma unroll
            for (int mt = 0; mt < 4; ++mt)
#pragma unroll
                for (int nt = 0; nt < 4; ++nt)
                    acc[mt][nt] = __builtin_amdgcn_mfma_f32_16x16x32_bf16(af[mt], bf[nt], acc[mt][nt], 0, 0, 0);
        }
        __syncthreads();
    }

    // Epilogue: +b', max over the wave's 64 cols, 16-lane reduce, write partial.
    const int colBase = blockN + wc * 64;
    const int rowBase = blockM + wr * 64;
    float bv[4];
#pragma unroll
    for (int nt = 0; nt < 4; ++nt) bv[nt] = bp[colBase + nt * 16 + r];

    float mx[4][4];
#pragma unroll
    for (int mt = 0; mt < 4; ++mt)
#pragma unroll
        for (int reg = 0; reg < 4; ++reg) {
            float v = acc[mt][0][reg] + bv[0];
            v = fmaxf(v, acc[mt][1][reg] + bv[1]);
            v = fmaxf(v, acc[mt][2][reg] + bv[2]);
            v = fmaxf(v, acc[mt][3][reg] + bv[3]);
            mx[mt][reg] = v;
        }
#pragma unroll
    for (int off = 1; off < 16; off <<= 1)
#pragma unroll
        for (int mt = 0; mt < 4; ++mt)
#pragma unroll
            for (int reg = 0; reg < 4; ++reg)
                mx[mt][reg] = fmaxf(mx[mt][reg], __shfl_xor(mx[mt][reg], off));

    if (r == 0) {
#pragma unroll
        for (int mt = 0; mt < 4; ++mt)
#pragma unroll
            for (int reg = 0; reg < 4; ++reg) {
                const int row = rowBase + mt * 16 + q * 4 + reg;
                partials[(size_t)row * 32 + nIdx * 2 + wc] = mx[mt][reg];
            }
    }
}

// ---------------------------------------------------------------------------
// reduce: 32 partials per row -> final max
// ---------------------------------------------------------------------------
__global__ __launch_bounds__(256) void reduce_kernel(
    const float4* __restrict__ partials, float* __restrict__ out) {
    const int row = blockIdx.x * blockDim.x + threadIdx.x;
    const float4* p = partials + (size_t)row * 8;
    float m = -INFINITY;
#pragma unroll
    for (int i = 0; i < 8; ++i) {
        float4 v = p[i];
        m = fmaxf(m, fmaxf(fmaxf(v.x, v.y), fmaxf(v.z, v.w)));
    }
    out[row] = m;
}

// ---------------------------------------------------------------------------
extern "C" void kernel_launch(void* const* d_in, const int* in_sizes, int n_in,
                              void* d_out, int out_size, void* d_ws, size_t ws_size,
                              hipStream_t stream) {
    const float* x   = (const float*)d_in[0];
    const float* l1w = (const float*)d_in[1];
    const float* l1b = (const float*)d_in[2];
    const float* w2  = (const float*)d_in[3];
    const float* b2  = (const float*)d_in[4];
    float* out = (float*)d_out;

    char* ws = (char*)d_ws;
    unsigned short* w1t = (unsigned short*)(ws);                 //  1 MB  w1^T bf16 [512,1024]
    unsigned short* w2b = (unsigned short*)(ws + 1048576);       //  4 MB  w2 bf16 [2048,1024]
    unsigned short* Wb  = (unsigned short*)(ws + 5242880);       //  2 MB  W bf16 [2048,512]
    float* bp           = (float*)(ws + 7340032);                //  8 KB  b' fp32 [2048]
    unsigned short* xb  = (unsigned short*)(ws + 7348224);       // 32 MB  x bf16 [32768,512]
    float* partials     = (float*)(ws + 40902656);               //  4 MB  [BATCH,32]

    // 1) fused pre-work: w1 transpose + w2 cvt(+bgemv) + x cvt  (single stream)
    prep_kernel<<<18944, 256, 0, stream>>>(
        l1w, (const float4*)w2, (const float4*)x, l1b, b2,
        w1t, (ushort4*)w2b, (ushort4*)xb, bp);

    // 2) W = w2b @ w1t^T  [2048, 512]  (256 blocks, BK=128)
    gemmW_kernel<<<dim3(DIN / 64, DOUT / 64), 256, 0, stream>>>(w2b, w1t, Wb);

    // 3) scores = xb @ W^T + b', fused row-max (one 4096-block dispatch)
    gemmS_kernel<<<4096, 256, 0, stream>>>(xb, Wb, bp, partials);

    // 4) final max over 32 partials per row
    reduce_kernel<<<BATCH / 256, 256, 0, stream>>>((const float4*)partials, out);
}